// Round 7
// baseline (1923.866 us; speedup 1.0000x reference)
//
#include <hip/hip_runtime.h>
#include <stdint.h>

#define D 256
#define NCLS 8
#define CLSZ 12500          // nodes per class (n = 100000)
#define NCH 8               // edge chunks

typedef __attribute__((ext_vector_type(4))) float f32x4;
typedef __attribute__((ext_vector_type(8))) short bf16x8;
typedef __attribute__((ext_vector_type(4))) unsigned short u16x4;

static __device__ __forceinline__ float bf2f(unsigned short u) {
  union { unsigned int i; float f; } x; x.i = ((unsigned int)u) << 16; return x.f;
}
static __device__ __forceinline__ unsigned short f2bf(float f) {
  union { float f; unsigned int i; } x; x.f = f;
  unsigned int u = x.i;
  return (unsigned short)((u + 0x7fffu + ((u >> 16) & 1u)) >> 16);
}

// ---------- khist8: atomic-free degree histogram (LDS bins, private parts) ----------
// hist_part[cls][ch][CLSZ]
__global__ __launch_bounds__(512) void khist8(const int* __restrict__ dst,
                                              int* __restrict__ hist_part, int E) {
  __shared__ int lh[CLSZ];
  int cls = blockIdx.x & (NCLS - 1);
  int ch = blockIdx.x >> 3;
  for (int i = threadIdx.x; i < CLSZ; i += 512) lh[i] = 0;
  __syncthreads();
  int lo = cls * CLSZ;
  int chunk = (E + NCH - 1) / NCH;
  int s = ch * chunk, e = min(E, s + chunk);
  for (int i = s + threadIdx.x; i < e; i += 512) {
    int d = dst[i];
    if ((unsigned)(d - lo) < (unsigned)CLSZ) atomicAdd(&lh[d - lo], 1);
  }
  __syncthreads();
  int* out = hist_part + ((size_t)cls * NCH + ch) * CLSZ;
  for (int i = threadIdx.x; i < CLSZ; i += 512) out[i] = lh[i];
}

// ---------- scan A: sum parts -> deg, dis; per-block exclusive scan ----------
__global__ __launch_bounds__(256) void kscanA(const int* __restrict__ hist_part,
                                              int* __restrict__ offsets,
                                              int* __restrict__ bsum,
                                              float* __restrict__ dis, int n) {
  __shared__ int sm[256];
  int t = threadIdx.x;
  int i = blockIdx.x * 256 + t;
  int c = 0;
  if (i < n) {
    int cls = i / CLSZ, loc = i - cls * CLSZ;
    const int* bp = hist_part + (size_t)cls * NCH * CLSZ + loc;
#pragma unroll
    for (int ch = 0; ch < NCH; ch++) c += bp[(size_t)ch * CLSZ];
    dis[i] = rsqrtf((float)(c + 1));   // +1 self loop
  }
  sm[t] = c; __syncthreads();
  int val = c;
  for (int d = 1; d < 256; d <<= 1) {
    int add = (t >= d) ? sm[t - d] : 0;
    __syncthreads();
    val += add;
    sm[t] = val;
    __syncthreads();
  }
  if (i < n) offsets[i] = val - c;
  if (t == 255) bsum[blockIdx.x] = val;
}

__global__ __launch_bounds__(512) void kscanB(int* __restrict__ bsum, int NB) {
  __shared__ int sm[512];
  int t = threadIdx.x;
  int c = (t < NB) ? bsum[t] : 0;
  sm[t] = c; __syncthreads();
  int val = c;
  for (int d = 1; d < 512; d <<= 1) {
    int add = (t >= d) ? sm[t - d] : 0;
    __syncthreads();
    val += add;
    sm[t] = val;
    __syncthreads();
  }
  if (t < NB) bsum[t] = val - c;
}

// ---------- scan C: final offsets + per-chunk placement bases ----------
__global__ __launch_bounds__(256) void kscanC(int* __restrict__ offsets,
                                              const int* __restrict__ bsum,
                                              const int* __restrict__ hist_part,
                                              int* __restrict__ base, int n, int E) {
  int i = blockIdx.x * 256 + threadIdx.x;
  if (i < n) {
    int o = offsets[i] + bsum[i >> 8];
    offsets[i] = o;
    int cls = i / CLSZ, loc = i - cls * CLSZ;
    const int* bp = hist_part + (size_t)cls * NCH * CLSZ + loc;
    int acc = o;
#pragma unroll
    for (int ch = 0; ch < NCH; ch++) {
      base[(size_t)ch * n + i] = acc;
      acc += bp[(size_t)ch * CLSZ];
    }
  }
  if (i == 0) offsets[n] = E;
}

// ---------- kwacc8: wacc[s] = sum_{e:src=s} dis[dst], LDS bins, private parts ----------
__global__ __launch_bounds__(512) void kwacc8(const int* __restrict__ src,
                                              const int* __restrict__ dst,
                                              const float* __restrict__ dis,
                                              float* __restrict__ wacc_part, int E) {
  __shared__ float lw[CLSZ];
  int cls = blockIdx.x & (NCLS - 1);
  int ch = blockIdx.x >> 3;
  for (int i = threadIdx.x; i < CLSZ; i += 512) lw[i] = 0.f;
  __syncthreads();
  int lo = cls * CLSZ;
  int chunk = (E + NCH - 1) / NCH;
  int s0 = ch * chunk, e0 = min(E, s0 + chunk);
  for (int i = s0 + threadIdx.x; i < e0; i += 512) {
    int s = src[i];
    if ((unsigned)(s - lo) < (unsigned)CLSZ) atomicAdd(&lw[s - lo], dis[dst[i]]);
  }
  __syncthreads();
  float* out = wacc_part + ((size_t)cls * NCH + ch) * CLSZ;
  for (int i = threadIdx.x; i < CLSZ; i += 512) out[i] = lw[i];
}

// ---------- reduce wacc parts ----------
__global__ __launch_bounds__(256) void kwaccred(const float* __restrict__ wacc_part,
                                                float* __restrict__ wacc, int n) {
  int i = blockIdx.x * 256 + threadIdx.x;
  if (i >= n) return;
  int cls = i / CLSZ, loc = i - cls * CLSZ;
  const float* bp = wacc_part + (size_t)cls * NCH * CLSZ + loc;
  float a = 0.f;
#pragma unroll
  for (int ch = 0; ch < NCH; ch++) a += bp[(size_t)ch * CLSZ];
  wacc[i] = a;
}

// ---------- kplace: counting-sort placement with LDS cursors (no global atomics) ----------
__global__ __launch_bounds__(512) void kplace(const int* __restrict__ src,
                                              const int* __restrict__ dst,
                                              const int* __restrict__ base,
                                              int* __restrict__ ssrc, int E, int n) {
  __shared__ int cur[CLSZ];
  int cls = blockIdx.x & (NCLS - 1);
  int ch = blockIdx.x >> 3;
  int lo = cls * CLSZ;
  for (int i = threadIdx.x; i < CLSZ; i += 512) cur[i] = base[(size_t)ch * n + lo + i];
  __syncthreads();
  int chunk = (E + NCH - 1) / NCH;
  int s0 = ch * chunk, e0 = min(E, s0 + chunk);
  for (int i = s0 + threadIdx.x; i < e0; i += 512) {
    int d = dst[i];
    if ((unsigned)(d - lo) < (unsigned)CLSZ) {
      int p = atomicAdd(&cur[d - lo], 1);   // LDS atomic, returns slot
      ssrc[p] = src[i];
    }
  }
}

// ---------- W1 (fp32, [k][n]) -> w1t (bf16, [n][k]) ----------
__global__ __launch_bounds__(256) void kw1t(const float* __restrict__ w1,
                                            unsigned short* __restrict__ w1t) {
  int idx = blockIdx.x * 256 + threadIdx.x;   // 65536
  int k = idx >> 8, nn = idx & 255;
  w1t[(size_t)nn * D + k] = f2bf(w1[idx]);
}

// ---------- kh: h = bf16(x @ W1), 32-row tiles, MFMA ----------
__global__ __launch_bounds__(256) void kh(const float* __restrict__ x,
                                          const unsigned short* __restrict__ w1t,
                                          unsigned short* __restrict__ h, int n) {
  __shared__ unsigned short As[32 * 264];
  __shared__ unsigned short Bs[256 * 40];
  int tid = threadIdx.x;
  int wv = tid >> 6, l = tid & 63, lr = l & 15, lh = l >> 4;
  int r0 = blockIdx.x * 32;

  {
    int row = tid >> 3, cb = (tid & 7) * 32;
    const float4* g = (const float4*)(x + (size_t)(r0 + row) * D + cb);
    u16x4 tmp[8];
#pragma unroll
    for (int j = 0; j < 8; j++) {
      float4 v = g[j];
      u16x4 o; o.x = f2bf(v.x); o.y = f2bf(v.y); o.z = f2bf(v.z); o.w = f2bf(v.w);
      tmp[j] = o;
    }
#pragma unroll
    for (int j = 0; j < 8; j++) *(u16x4*)&As[row * 264 + cb + j * 4] = tmp[j];
  }

  f32x4 acc[2][4];
#pragma unroll
  for (int m = 0; m < 2; m++)
#pragma unroll
    for (int f = 0; f < 4; f++) acc[m][f] = (f32x4){0.f, 0.f, 0.f, 0.f};

  for (int kk = 0; kk < 8; ++kk) {
    __syncthreads();
    {
      const int4* g = (const int4*)(w1t + (size_t)tid * D + kk * 32);
#pragma unroll
      for (int j = 0; j < 4; j++) *(int4*)&Bs[tid * 40 + j * 8] = g[j];
    }
    __syncthreads();

    bf16x8 af[2];
#pragma unroll
    for (int m = 0; m < 2; m++)
      af[m] = *(const bf16x8*)&As[(m * 16 + lr) * 264 + kk * 32 + lh * 8];
    bf16x8 bfr[4];
#pragma unroll
    for (int f = 0; f < 4; f++)
      bfr[f] = *(const bf16x8*)&Bs[(wv * 64 + f * 16 + lr) * 40 + lh * 8];
#pragma unroll
    for (int m = 0; m < 2; m++)
#pragma unroll
      for (int f = 0; f < 4; f++)
        acc[m][f] = __builtin_amdgcn_mfma_f32_16x16x32_bf16(af[m], bfr[f], acc[m][f], 0, 0, 0);
  }

  __syncthreads();
#pragma unroll
  for (int m = 0; m < 2; m++)
#pragma unroll
    for (int f = 0; f < 4; f++)
#pragma unroll
      for (int j = 0; j < 4; j++)
        As[(m * 16 + lh * 4 + j) * 264 + wv * 64 + f * 16 + lr] = f2bf(acc[m][f][j]);
  __syncthreads();
  {
    int row = tid >> 3, cb = (tid & 7) * 32;
#pragma unroll
    for (int j = 0; j < 4; j++) {
      int4 v = *(const int4*)&As[row * 264 + cb + j * 8];
      *(int4*)(h + (size_t)(r0 + row) * D + cb + j * 8) = v;
    }
  }
}

// ---------- kagg2: gather h rows, +b1, relu, weighted col-sum -> vpart ----------
__global__ __launch_bounds__(256) void kagg2(const unsigned short* __restrict__ h,
                                             const int* __restrict__ offsets,
                                             const int* __restrict__ ssrc,
                                             const float* __restrict__ dis,
                                             const float* __restrict__ wacc,
                                             const float* __restrict__ b1,
                                             float* __restrict__ vpart, int n) {
  __shared__ float sm[4][256];
  int tid = threadIdx.x, wv = tid >> 6, l = tid & 63;
  int c0 = l * 4;
  float4 bb = *(const float4*)(b1 + c0);
  float v0 = 0.f, v1 = 0.f, v2 = 0.f, v3 = 0.f;
  int base = blockIdx.x * 16 + wv * 4;

  for (int k = 0; k < 4; ++k) {
    int node = base + k;
    float di = dis[node];
    u16x4 sx = *(const u16x4*)(h + (size_t)node * D + c0);
    float dii = di * di;
    float a0 = bf2f(sx.x) * dii, a1 = bf2f(sx.y) * dii;
    float a2 = bf2f(sx.z) * dii, a3 = bf2f(sx.w) * dii;
    int e0 = offsets[node], e1 = offsets[node + 1];
    int e = e0;
    for (; e + 8 <= e1; e += 8) {
      int sidx[8]; float nm[8]; u16x4 xv[8];
#pragma unroll
      for (int j = 0; j < 8; j++) sidx[j] = ssrc[e + j];
#pragma unroll
      for (int j = 0; j < 8; j++) nm[j] = dis[sidx[j]] * di;
#pragma unroll
      for (int j = 0; j < 8; j++) xv[j] = *(const u16x4*)(h + (size_t)sidx[j] * D + c0);
#pragma unroll
      for (int j = 0; j < 8; j++) {
        a0 = fmaf(bf2f(xv[j].x), nm[j], a0);
        a1 = fmaf(bf2f(xv[j].y), nm[j], a1);
        a2 = fmaf(bf2f(xv[j].z), nm[j], a2);
        a3 = fmaf(bf2f(xv[j].w), nm[j], a3);
      }
    }
    for (; e + 4 <= e1; e += 4) {
      int sidx[4]; float nm[4]; u16x4 xv[4];
#pragma unroll
      for (int j = 0; j < 4; j++) sidx[j] = ssrc[e + j];
#pragma unroll
      for (int j = 0; j < 4; j++) nm[j] = dis[sidx[j]] * di;
#pragma unroll
      for (int j = 0; j < 4; j++) xv[j] = *(const u16x4*)(h + (size_t)sidx[j] * D + c0);
#pragma unroll
      for (int j = 0; j < 4; j++) {
        a0 = fmaf(bf2f(xv[j].x), nm[j], a0);
        a1 = fmaf(bf2f(xv[j].y), nm[j], a1);
        a2 = fmaf(bf2f(xv[j].z), nm[j], a2);
        a3 = fmaf(bf2f(xv[j].w), nm[j], a3);
      }
    }
    for (; e < e1; ++e) {
      int s = ssrc[e];
      float nm = dis[s] * di;
      u16x4 xv = *(const u16x4*)(h + (size_t)s * D + c0);
      a0 = fmaf(bf2f(xv.x), nm, a0); a1 = fmaf(bf2f(xv.y), nm, a1);
      a2 = fmaf(bf2f(xv.z), nm, a2); a3 = fmaf(bf2f(xv.w), nm, a3);
    }
    float w = di * wacc[node] + dii;
    a0 += bb.x; a1 += bb.y; a2 += bb.z; a3 += bb.w;
    a0 = a0 > 0.f ? a0 : 0.f; a1 = a1 > 0.f ? a1 : 0.f;
    a2 = a2 > 0.f ? a2 : 0.f; a3 = a3 > 0.f ? a3 : 0.f;
    v0 = fmaf(w, a0, v0); v1 = fmaf(w, a1, v1);
    v2 = fmaf(w, a2, v2); v3 = fmaf(w, a3, v3);
  }

  f32x4 vv; vv[0] = v0; vv[1] = v1; vv[2] = v2; vv[3] = v3;
  *(f32x4*)&sm[wv][c0] = vv;
  __syncthreads();
  float r = sm[0][tid & 255] + sm[1][tid & 255] + sm[2][tid & 255] + sm[3][tid & 255];
  vpart[(size_t)blockIdx.x * D + tid] = r;
}

// ---------- reduce vpart -> v ----------
__global__ __launch_bounds__(256) void kvred(const float* __restrict__ vpart,
                                             float* __restrict__ v, int nb) {
  int c = threadIdx.x;
  float acc = 0.f;
  for (int r = blockIdx.x; r < nb; r += gridDim.x) acc += vpart[(size_t)r * D + c];
  atomicAdd(&v[c], acc);
}

// ---------- out[c] = (v . W2[:,c])/n + b2[c] ----------
__global__ __launch_bounds__(256) void kout(const float* __restrict__ v,
                                            const float* __restrict__ w2,
                                            const float* __restrict__ b2,
                                            float* __restrict__ out, float invn) {
  __shared__ float sm[256];
  int c = blockIdx.x, t = threadIdx.x;
  sm[t] = v[t] * w2[t * D + c];
  __syncthreads();
  for (int d = 128; d > 0; d >>= 1) {
    if (t < d) sm[t] += sm[t + d];
    __syncthreads();
  }
  if (t == 0) out[c] = sm[0] * invn + b2[c];
}

extern "C" void kernel_launch(void* const* d_in, const int* in_sizes, int n_in,
                              void* d_out, int out_size, void* d_ws, size_t ws_size,
                              hipStream_t stream) {
  const float* x  = (const float*)d_in[0];
  const float* W1 = (const float*)d_in[1];
  const float* b1 = (const float*)d_in[2];
  const float* W2 = (const float*)d_in[3];
  const float* b2 = (const float*)d_in[4];
  const int* ei = (const int*)d_in[5];

  int n = in_sizes[0] / D;   // 100000
  int E = in_sizes[5] / 2;   // 3200000
  const int* srcp = ei;
  const int* dstp = ei + E;

  char* p = (char*)d_ws;
  float* v    = (float*)p;    p += 256 * 4;            // zeroed
  float* dis  = (float*)p;    p += (size_t)n * 4;
  float* wacc = (float*)p;    p += (size_t)n * 4;
  int* offsets = (int*)p;     p += (size_t)(n + 1) * 4;
  p = (char*)(((uintptr_t)p + 255) & ~(uintptr_t)255);
  int* bsum = (int*)p;        p += 1024 * 4;
  int* hist_part = (int*)p;   p += (size_t)NCLS * NCH * CLSZ * 4;   // 3.2 MB
  float* wacc_part = (float*)p; p += (size_t)NCLS * NCH * CLSZ * 4; // 3.2 MB
  int* base = (int*)p;        p += (size_t)NCH * n * 4;             // 3.2 MB
  int* ssrc = (int*)p;        p += (size_t)E * 4;
  p = (char*)(((uintptr_t)p + 255) & ~(uintptr_t)255);
  float* vpart = (float*)p;   p += (size_t)(n / 16) * D * 4;
  p = (char*)(((uintptr_t)p + 255) & ~(uintptr_t)255);
  unsigned short* h = (unsigned short*)p;    p += (size_t)n * D * 2;
  p = (char*)(((uintptr_t)p + 255) & ~(uintptr_t)255);
  unsigned short* w1t = (unsigned short*)p;  p += (size_t)D * D * 2;

  int NB = (n + 255) / 256;

  hipMemsetAsync(v, 0, 256 * 4, stream);
  khist8<<<NCLS * NCH, 512, 0, stream>>>(dstp, hist_part, E);
  kscanA<<<NB, 256, 0, stream>>>(hist_part, offsets, bsum, dis, n);
  kscanB<<<1, 512, 0, stream>>>(bsum, NB);
  kscanC<<<NB, 256, 0, stream>>>(offsets, bsum, hist_part, base, n, E);
  kwacc8<<<NCLS * NCH, 512, 0, stream>>>(srcp, dstp, dis, wacc_part, E);
  kwaccred<<<NB, 256, 0, stream>>>(wacc_part, wacc, n);
  kplace<<<NCLS * NCH, 512, 0, stream>>>(srcp, dstp, base, ssrc, E, n);
  kw1t<<<(D * D) / 256, 256, 0, stream>>>(W1, w1t);
  kh<<<n / 32, 256, 0, stream>>>(x, w1t, h, n);
  kagg2<<<n / 16, 256, 0, stream>>>(h, offsets, ssrc, dis, wacc, b1, vpart, n);
  kvred<<<64, 256, 0, stream>>>(vpart, v, n / 16);
  kout<<<256, 256, 0, stream>>>(v, W2, b2, (float*)d_out, 1.0f / (float)n);
}